// Round 1
// baseline (264.325 us; speedup 1.0000x reference)
//
#include <hip/hip_runtime.h>
#include <math.h>

#define BB 64
#define SS 32
#define DD 1024
#define HH 1024
#define DSPLIT 4
#define DS (DD / DSPLIT)   // 256 rows per split
#define PMAX 8

__device__ __forceinline__ float gelu_exact(float x) {
    return 0.5f * x * (1.0f + erff(x * 0.7071067811865476f));
}

// ---------------- Kernel A: scene logits, log-softmax, argmax ----------------
// grid: 64 blocks (one per sample b), 256 threads (4 waves; wave w handles scenes w*8..w*8+7)
__global__ __launch_bounds__(256) void scene_kernel(
    const float* __restrict__ descs_t, const float* __restrict__ descs_rot,
    const float* __restrict__ scene_w, const float* __restrict__ scene_b,
    float* __restrict__ out, int* __restrict__ idx_ws)
{
    const int b = blockIdx.x;
    const int tid = threadIdx.x;
    const int wave = tid >> 6, lane = tid & 63;

    __shared__ float sh_logits[SS];
    __shared__ float sh_stats[2];   // max, log-sum-exp

    const float* tb = descs_t  + (size_t)b * SS * DD;
    const float* rb = descs_rot + (size_t)b * SS * DD;
    const float4* w4t = (const float4*)(scene_w);
    const float4* w4r = (const float4*)(scene_w + DD);

    for (int s = wave * 8; s < wave * 8 + 8; ++s) {
        const float4* t4 = (const float4*)(tb + (size_t)s * DD);
        const float4* r4 = (const float4*)(rb + (size_t)s * DD);
        float acc = 0.f;
        #pragma unroll
        for (int c = 0; c < 4; ++c) {
            float4 a = t4[c * 64 + lane];
            float4 w = w4t[c * 64 + lane];
            acc += a.x*w.x + a.y*w.y + a.z*w.z + a.w*w.w;
            float4 a2 = r4[c * 64 + lane];
            float4 w2 = w4r[c * 64 + lane];
            acc += a2.x*w2.x + a2.y*w2.y + a2.z*w2.z + a2.w*w2.w;
        }
        #pragma unroll
        for (int off = 32; off >= 1; off >>= 1)
            acc += __shfl_xor(acc, off, 64);
        if (lane == 0) sh_logits[s] = acc + scene_b[0];
    }
    __syncthreads();

    if (tid == 0) {
        float m = sh_logits[0]; int am = 0;
        for (int s = 1; s < SS; ++s) {
            if (sh_logits[s] > m) { m = sh_logits[s]; am = s; }  // first-max tie-break
        }
        float sum = 0.f;
        for (int s = 0; s < SS; ++s) sum += expf(sh_logits[s] - m);
        sh_stats[0] = m;
        sh_stats[1] = logf(sum);
        idx_ws[b] = am;
    }
    __syncthreads();

    if (tid < SS) {
        // output layout: [0, 448) = expected_pose [64][7]; [448, 2496) = scene_log_distr [64][32]
        out[BB * 7 + b * SS + tid] = sh_logits[tid] - sh_stats[0] - sh_stats[1];
    }
}

// ---------------- Kernel B: layer-1 matvec, grouped by scene ----------------
// grid: (DSPLIT, SS, 2 heads); block 256 threads; each thread owns 4 consecutive H columns.
// Streams W1[s] (1 MB per block) exactly once per needed (s, head); up to PMAX samples/pass.
__global__ __launch_bounds__(256) void layer1_kernel(
    const float* __restrict__ descs_t, const float* __restrict__ descs_rot,
    const float* __restrict__ Wt1, const float* __restrict__ Wr1,
    const int* __restrict__ idx_ws, float* __restrict__ part)
{
    const int dsp  = blockIdx.x;   // d-split
    const int s    = blockIdx.y;   // scene
    const int head = blockIdx.z;   // 0 = t, 1 = rot
    const int tid  = threadIdx.x;

    __shared__ int   sh_list[BB];
    __shared__ int   sh_count;
    __shared__ float sh_g[PMAX][DS];   // 8 KB

    if (tid == 0) {
        int c = 0;
        for (int b = 0; b < BB; ++b) if (idx_ws[b] == s) sh_list[c++] = b;
        sh_count = c;
    }
    __syncthreads();
    const int count = sh_count;
    if (count == 0) return;

    const float* descs = head ? descs_rot : descs_t;
    const float* W = (head ? Wr1 : Wt1) + (size_t)s * DD * HH;
    const int j  = tid * 4;
    const int d0 = dsp * DS;

    for (int p0 = 0; p0 < count; p0 += PMAX) {
        const int nb = min(PMAX, count - p0);

        // cooperative load of the d-slice of each sample's g vector (nb * 1 KB)
        for (int t = tid; t < nb * (DS / 4); t += 256) {
            int p = t >> 6;          // DS/4 == 64
            int c = t & 63;
            int b = sh_list[p0 + p];
            const float4* src = (const float4*)(descs + ((size_t)b * SS + s) * DD + d0);
            ((float4*)sh_g[p])[c] = src[c];
        }
        __syncthreads();

        float4 acc[PMAX];
        #pragma unroll
        for (int p = 0; p < PMAX; ++p) acc[p] = make_float4(0.f, 0.f, 0.f, 0.f);

        const float* Wd = W + (size_t)d0 * HH + j;
        #pragma unroll 4
        for (int d = 0; d < DS; ++d) {
            float4 w = *(const float4*)(Wd + (size_t)d * HH);
            #pragma unroll
            for (int p = 0; p < PMAX; ++p) {
                if (p < nb) {
                    float g = sh_g[p][d];
                    acc[p].x += g * w.x;
                    acc[p].y += g * w.y;
                    acc[p].z += g * w.z;
                    acc[p].w += g * w.w;
                }
            }
        }

        #pragma unroll
        for (int p = 0; p < PMAX; ++p) {
            if (p < nb) {
                int b = sh_list[p0 + p];
                float* dst = part + (((size_t)(head * BB + b) * DSPLIT + dsp) * HH) + j;
                *(float4*)dst = acc[p];
            }
        }
        __syncthreads();
    }
}

// ---------------- Kernel C: bias + GELU, layer-2 (7 tiny dots), pose output ----------------
// grid: 64 blocks (one per sample), 256 threads.
__global__ __launch_bounds__(256) void head_out_kernel(
    const float* __restrict__ bt1, const float* __restrict__ Wt2, const float* __restrict__ bt2,
    const float* __restrict__ br1, const float* __restrict__ Wr2, const float* __restrict__ br2,
    const int* __restrict__ idx_ws, const float* __restrict__ part,
    float* __restrict__ out)
{
    const int b   = blockIdx.x;
    const int tid = threadIdx.x;
    const int s   = idx_ws[b];

    __shared__ float sh_h[2][HH];     // 8 KB
    __shared__ float sh_red[7][4];

    #pragma unroll
    for (int head = 0; head < 2; ++head) {
        const float* b1 = (head ? br1 : bt1) + (size_t)s * HH;
        const float* p0 = part + ((size_t)(head * BB + b) * DSPLIT) * HH;
        const int j = tid * 4;
        float4 a = *(const float4*)(p0 + j);
        #pragma unroll
        for (int dsp = 1; dsp < DSPLIT; ++dsp) {
            float4 q = *(const float4*)(p0 + (size_t)dsp * HH + j);
            a.x += q.x; a.y += q.y; a.z += q.z; a.w += q.w;
        }
        float4 bb = *(const float4*)(b1 + j);
        sh_h[head][j + 0] = gelu_exact(a.x + bb.x);
        sh_h[head][j + 1] = gelu_exact(a.y + bb.y);
        sh_h[head][j + 2] = gelu_exact(a.z + bb.z);
        sh_h[head][j + 3] = gelu_exact(a.w + bb.w);
    }
    __syncthreads();

    const float* wt2 = Wt2 + (size_t)s * HH * 3;
    const float* wr2 = Wr2 + (size_t)s * HH * 4;
    float pa[7] = {0.f, 0.f, 0.f, 0.f, 0.f, 0.f, 0.f};
    for (int j = tid; j < HH; j += 256) {
        float ht = sh_h[0][j];
        float hr = sh_h[1][j];
        pa[0] += ht * wt2[j * 3 + 0];
        pa[1] += ht * wt2[j * 3 + 1];
        pa[2] += ht * wt2[j * 3 + 2];
        pa[3] += hr * wr2[j * 4 + 0];
        pa[4] += hr * wr2[j * 4 + 1];
        pa[5] += hr * wr2[j * 4 + 2];
        pa[6] += hr * wr2[j * 4 + 3];
    }
    const int lane = tid & 63, wave = tid >> 6;
    #pragma unroll
    for (int o = 0; o < 7; ++o) {
        float v = pa[o];
        #pragma unroll
        for (int off = 32; off >= 1; off >>= 1) v += __shfl_xor(v, off, 64);
        if (lane == 0) sh_red[o][wave] = v;
    }
    __syncthreads();
    if (tid < 7) {
        float v = sh_red[tid][0] + sh_red[tid][1] + sh_red[tid][2] + sh_red[tid][3];
        float bias = (tid < 3) ? bt2[(size_t)s * 3 + tid] : br2[(size_t)s * 4 + (tid - 3)];
        out[b * 7 + tid] = v + bias;
    }
}

extern "C" void kernel_launch(void* const* d_in, const int* in_sizes, int n_in,
                              void* d_out, int out_size, void* d_ws, size_t ws_size,
                              hipStream_t stream) {
    const float* descs_t   = (const float*)d_in[0];
    const float* descs_rot = (const float*)d_in[1];
    const float* scene_w   = (const float*)d_in[2];
    const float* scene_b   = (const float*)d_in[3];
    const float* Wt1 = (const float*)d_in[4];
    const float* bt1 = (const float*)d_in[5];
    const float* Wt2 = (const float*)d_in[6];
    const float* bt2 = (const float*)d_in[7];
    const float* Wr1 = (const float*)d_in[8];
    const float* br1 = (const float*)d_in[9];
    const float* Wr2 = (const float*)d_in[10];
    const float* br2 = (const float*)d_in[11];
    float* out = (float*)d_out;

    // workspace layout: [0,256) idx (int[64]); [256, 256+2MB) layer-1 partials
    int*   idx_ws = (int*)d_ws;
    float* part   = (float*)((char*)d_ws + 256);
    // part: [2 heads][64 b][DSPLIT][1024] floats = 2 MB; every entry written every call.

    scene_kernel<<<dim3(BB), dim3(256), 0, stream>>>(
        descs_t, descs_rot, scene_w, scene_b, out, idx_ws);
    layer1_kernel<<<dim3(DSPLIT, SS, 2), dim3(256), 0, stream>>>(
        descs_t, descs_rot, Wt1, Wr1, idx_ws, part);
    head_out_kernel<<<dim3(BB), dim3(256), 0, stream>>>(
        bt1, Wt2, bt2, br1, Wr2, br2, idx_ws, part, out);
}

// Round 2
// 63.704 us; speedup vs baseline: 4.1493x; 4.1493x over previous
//
#include <hip/hip_runtime.h>
#include <math.h>

#define BB 64
#define SS 32
#define DD 1024
#define HH 1024
#define PMAX 8

__device__ __forceinline__ float gelu_exact(float x) {
    return 0.5f * x * (1.0f + erff(x * 0.7071067811865476f));
}

// ws layout:
//   [0, 256)        idx int[64]
//   [256, 8448)     logits float[64][32]
//   [8448, 16640)   list  int[32][64]
//   [16640, 16768)  count int[32]
//   [32768, ...)    part  float[2][64][DSPL][1024]
#define WS_LOGITS 256
#define WS_LIST   8448
#define WS_COUNT  16640
#define WS_PART   32768

// ---------------- Kernel A1: one logit per block ----------------
// grid (SS, BB), block 256: dot(concat(t,rot), scene_w) for (b,s)
__global__ __launch_bounds__(256) void logits_kernel(
    const float* __restrict__ descs_t, const float* __restrict__ descs_rot,
    const float* __restrict__ scene_w, float* __restrict__ logits)
{
    const int s = blockIdx.x, b = blockIdx.y;
    const int tid = threadIdx.x, lane = tid & 63, wave = tid >> 6;

    const float4* t4 = (const float4*)(descs_t  + ((size_t)b * SS + s) * DD);
    const float4* r4 = (const float4*)(descs_rot + ((size_t)b * SS + s) * DD);
    const float4* w4t = (const float4*)(scene_w);
    const float4* w4r = (const float4*)(scene_w + DD);

    float4 a = t4[tid], w = w4t[tid];
    float acc = a.x*w.x + a.y*w.y + a.z*w.z + a.w*w.w;
    float4 a2 = r4[tid], w2 = w4r[tid];
    acc += a2.x*w2.x + a2.y*w2.y + a2.z*w2.z + a2.w*w2.w;

    #pragma unroll
    for (int off = 32; off >= 1; off >>= 1) acc += __shfl_xor(acc, off, 64);

    __shared__ float red[4];
    if (lane == 0) red[wave] = acc;
    __syncthreads();
    if (tid == 0) logits[b * SS + s] = red[0] + red[1] + red[2] + red[3];
}

// ---------------- Kernel A2: softmax/argmax/list-build (1 wave) ----------------
// grid 1, block 64; lane b owns sample b.
__global__ __launch_bounds__(64) void finalize_scene_kernel(
    const float* __restrict__ scene_b, float* __restrict__ logits,
    int* __restrict__ idx_ws, int* __restrict__ list, int* __restrict__ count,
    float* __restrict__ out)
{
    const int b = threadIdx.x;
    const float bias = scene_b[0];
    float lg[SS];
    float m = -1e30f; int am = 0;
    #pragma unroll
    for (int s = 0; s < SS; ++s) {
        lg[s] = logits[b * SS + s] + bias;
        if (lg[s] > m) { m = lg[s]; am = s; }   // first-max tie-break
    }
    float sum = 0.f;
    #pragma unroll
    for (int s = 0; s < SS; ++s) sum += expf(lg[s] - m);
    const float lse = m + logf(sum);
    #pragma unroll
    for (int s = 0; s < SS; ++s) out[BB * 7 + b * SS + s] = lg[s] - lse;
    idx_ws[b] = am;

    // per-scene sample lists via ballot (64 samples == 64 lanes)
    for (int s = 0; s < SS; ++s) {
        unsigned long long mk = __ballot(am == s);
        if (am == s) {
            int rank = __popcll(mk & ((1ull << b) - 1ull));
            list[s * BB + rank] = b;
        }
        if (b == 0) count[s] = (int)__popcll(mk);
    }
}

// ---------------- Kernel B: layer-1 matvec, grouped by scene ----------------
template<int DSPL>
__global__ __launch_bounds__(256) void layer1_kernel(
    const float* __restrict__ descs_t, const float* __restrict__ descs_rot,
    const float* __restrict__ Wt1, const float* __restrict__ Wr1,
    const int* __restrict__ list, const int* __restrict__ count,
    float* __restrict__ part)
{
    constexpr int DS = DD / DSPL;
    const int dsp  = blockIdx.x;
    const int s    = blockIdx.y;
    const int head = blockIdx.z;
    const int tid  = threadIdx.x;

    const int cnt = count[s];
    if (cnt == 0) return;

    __shared__ int   sh_list[BB];
    __shared__ float sh_g[PMAX][DS];
    if (tid < BB) sh_list[tid] = list[s * BB + tid];

    const float* descs = head ? descs_rot : descs_t;
    const float* W = (head ? Wr1 : Wt1) + (size_t)s * DD * HH;
    const int j  = tid * 4;
    const int d0 = dsp * DS;

    for (int p0 = 0; p0 < cnt; p0 += PMAX) {
        const int nb = min(PMAX, cnt - p0);
        __syncthreads();
        // load g slices for live samples; zero-pad the rest (branch-free compute)
        for (int t = tid; t < PMAX * (DS / 4); t += 256) {
            const int p = t / (DS / 4);
            const int c = t % (DS / 4);
            float4 v = make_float4(0.f, 0.f, 0.f, 0.f);
            if (p < nb) {
                const int b = sh_list[p0 + p];
                v = ((const float4*)(descs + ((size_t)b * SS + s) * DD + d0))[c];
            }
            ((float4*)sh_g[p])[c] = v;
        }
        __syncthreads();

        float4 acc[PMAX];
        #pragma unroll
        for (int p = 0; p < PMAX; ++p) acc[p] = make_float4(0.f, 0.f, 0.f, 0.f);

        const float* Wd = W + (size_t)d0 * HH + j;
        #pragma unroll 2
        for (int d4 = 0; d4 < DS / 4; ++d4) {
            const float* r = Wd + (size_t)(d4 * 4) * HH;
            float4 w0 = *(const float4*)(r);
            float4 w1 = *(const float4*)(r + HH);
            float4 w2 = *(const float4*)(r + 2 * HH);
            float4 w3 = *(const float4*)(r + 3 * HH);
            #pragma unroll
            for (int p = 0; p < PMAX; ++p) {
                float4 g = ((const float4*)sh_g[p])[d4];
                acc[p].x += g.x * w0.x; acc[p].y += g.x * w0.y; acc[p].z += g.x * w0.z; acc[p].w += g.x * w0.w;
                acc[p].x += g.y * w1.x; acc[p].y += g.y * w1.y; acc[p].z += g.y * w1.z; acc[p].w += g.y * w1.w;
                acc[p].x += g.z * w2.x; acc[p].y += g.z * w2.y; acc[p].z += g.z * w2.z; acc[p].w += g.z * w2.w;
                acc[p].x += g.w * w3.x; acc[p].y += g.w * w3.y; acc[p].z += g.w * w3.z; acc[p].w += g.w * w3.w;
            }
        }

        #pragma unroll
        for (int p = 0; p < PMAX; ++p) {
            if (p < nb) {
                const int b = sh_list[p0 + p];
                float* dst = part + (((size_t)(head * BB + b) * DSPL + dsp) * HH) + j;
                *(float4*)dst = acc[p];
            }
        }
    }
}

// ---------------- Kernel C: bias + GELU + layer-2 + pose output ----------------
template<int DSPL>
__global__ __launch_bounds__(256) void head_out_kernel(
    const float* __restrict__ bt1, const float* __restrict__ Wt2, const float* __restrict__ bt2,
    const float* __restrict__ br1, const float* __restrict__ Wr2, const float* __restrict__ br2,
    const int* __restrict__ idx_ws, const float* __restrict__ part,
    float* __restrict__ out)
{
    const int b   = blockIdx.x;
    const int tid = threadIdx.x;
    const int s   = idx_ws[b];

    __shared__ float sh_h[2][HH];
    __shared__ float sh_red[7][4];

    #pragma unroll
    for (int head = 0; head < 2; ++head) {
        const float* b1 = (head ? br1 : bt1) + (size_t)s * HH;
        const float* p0 = part + ((size_t)(head * BB + b) * DSPL) * HH;
        const int j = tid * 4;
        float4 a = *(const float4*)(p0 + j);
        #pragma unroll
        for (int dsp = 1; dsp < DSPL; ++dsp) {
            float4 q = *(const float4*)(p0 + (size_t)dsp * HH + j);
            a.x += q.x; a.y += q.y; a.z += q.z; a.w += q.w;
        }
        float4 bb = *(const float4*)(b1 + j);
        sh_h[head][j + 0] = gelu_exact(a.x + bb.x);
        sh_h[head][j + 1] = gelu_exact(a.y + bb.y);
        sh_h[head][j + 2] = gelu_exact(a.z + bb.z);
        sh_h[head][j + 3] = gelu_exact(a.w + bb.w);
    }
    __syncthreads();

    const float* wt2 = Wt2 + (size_t)s * HH * 3;
    const float* wr2 = Wr2 + (size_t)s * HH * 4;
    float pa[7] = {0.f, 0.f, 0.f, 0.f, 0.f, 0.f, 0.f};
    for (int j = tid; j < HH; j += 256) {
        float ht = sh_h[0][j];
        float hr = sh_h[1][j];
        pa[0] += ht * wt2[j * 3 + 0];
        pa[1] += ht * wt2[j * 3 + 1];
        pa[2] += ht * wt2[j * 3 + 2];
        pa[3] += hr * wr2[j * 4 + 0];
        pa[4] += hr * wr2[j * 4 + 1];
        pa[5] += hr * wr2[j * 4 + 2];
        pa[6] += hr * wr2[j * 4 + 3];
    }
    const int lane = tid & 63, wave = tid >> 6;
    #pragma unroll
    for (int o = 0; o < 7; ++o) {
        float v = pa[o];
        #pragma unroll
        for (int off = 32; off >= 1; off >>= 1) v += __shfl_xor(v, off, 64);
        if (lane == 0) sh_red[o][wave] = v;
    }
    __syncthreads();
    if (tid < 7) {
        float v = sh_red[tid][0] + sh_red[tid][1] + sh_red[tid][2] + sh_red[tid][3];
        float bias = (tid < 3) ? bt2[(size_t)s * 3 + tid] : br2[(size_t)s * 4 + (tid - 3)];
        out[b * 7 + tid] = v + bias;
    }
}

template<int DSPL>
static void launch_pipeline(const float* descs_t, const float* descs_rot,
                            const float* Wt1, const float* Wr1,
                            const float* bt1, const float* Wt2, const float* bt2,
                            const float* br1, const float* Wr2, const float* br2,
                            int* idx_ws, int* list, int* count, float* part,
                            float* out, hipStream_t stream) {
    layer1_kernel<DSPL><<<dim3(DSPL, SS, 2), dim3(256), 0, stream>>>(
        descs_t, descs_rot, Wt1, Wr1, list, count, part);
    head_out_kernel<DSPL><<<dim3(BB), dim3(256), 0, stream>>>(
        bt1, Wt2, bt2, br1, Wr2, br2, idx_ws, part, out);
}

extern "C" void kernel_launch(void* const* d_in, const int* in_sizes, int n_in,
                              void* d_out, int out_size, void* d_ws, size_t ws_size,
                              hipStream_t stream) {
    const float* descs_t   = (const float*)d_in[0];
    const float* descs_rot = (const float*)d_in[1];
    const float* scene_w   = (const float*)d_in[2];
    const float* scene_b   = (const float*)d_in[3];
    const float* Wt1 = (const float*)d_in[4];
    const float* bt1 = (const float*)d_in[5];
    const float* Wt2 = (const float*)d_in[6];
    const float* bt2 = (const float*)d_in[7];
    const float* Wr1 = (const float*)d_in[8];
    const float* br1 = (const float*)d_in[9];
    const float* Wr2 = (const float*)d_in[10];
    const float* br2 = (const float*)d_in[11];
    float* out = (float*)d_out;

    int*   idx_ws = (int*)d_ws;
    float* logits = (float*)((char*)d_ws + WS_LOGITS);
    int*   list   = (int*)((char*)d_ws + WS_LIST);
    int*   count  = (int*)((char*)d_ws + WS_COUNT);
    float* part   = (float*)((char*)d_ws + WS_PART);

    logits_kernel<<<dim3(SS, BB), dim3(256), 0, stream>>>(
        descs_t, descs_rot, scene_w, logits);
    finalize_scene_kernel<<<dim3(1), dim3(64), 0, stream>>>(
        scene_b, logits, idx_ws, list, count, out);

    const size_t need32 = (size_t)WS_PART + (size_t)2 * BB * 32 * HH * sizeof(float);
    const size_t need16 = (size_t)WS_PART + (size_t)2 * BB * 16 * HH * sizeof(float);
    const size_t need8  = (size_t)WS_PART + (size_t)2 * BB * 8  * HH * sizeof(float);
    if (ws_size >= need32) {
        launch_pipeline<32>(descs_t, descs_rot, Wt1, Wr1, bt1, Wt2, bt2, br1, Wr2, br2,
                            idx_ws, list, count, part, out, stream);
    } else if (ws_size >= need16) {
        launch_pipeline<16>(descs_t, descs_rot, Wt1, Wr1, bt1, Wt2, bt2, br1, Wr2, br2,
                            idx_ws, list, count, part, out, stream);
    } else if (ws_size >= need8) {
        launch_pipeline<8>(descs_t, descs_rot, Wt1, Wr1, bt1, Wt2, bt2, br1, Wr2, br2,
                            idx_ws, list, count, part, out, stream);
    } else {
        launch_pipeline<4>(descs_t, descs_rot, Wt1, Wr1, bt1, Wt2, bt2, br1, Wr2, br2,
                            idx_ws, list, count, part, out, stream);
    }
}

// Round 3
// 63.550 us; speedup vs baseline: 4.1593x; 1.0024x over previous
//
#include <hip/hip_runtime.h>
#include <math.h>

#define BB 64
#define SS 32
#define DD 1024
#define HH 1024
#define PMAX 8

__device__ __forceinline__ float gelu_exact(float x) {
    return 0.5f * x * (1.0f + erff(x * 0.7071067811865476f));
}

// ws layout:
//   [0, 256)        idx int[64]
//   [256, 8448)     logits float[64][32]
//   [8448, 16640)   list  int[32][64]
//   [16640, 16768)  count int[32]
//   [32768, ...)    part  float[2][64][DSPL][1024]
#define WS_LOGITS 256
#define WS_LIST   8448
#define WS_COUNT  16640
#define WS_PART   32768

// ---------------- Kernel A1: one logit per block ----------------
__global__ __launch_bounds__(256) void logits_kernel(
    const float* __restrict__ descs_t, const float* __restrict__ descs_rot,
    const float* __restrict__ scene_w, float* __restrict__ logits)
{
    const int s = blockIdx.x, b = blockIdx.y;
    const int tid = threadIdx.x, lane = tid & 63, wave = tid >> 6;

    const float4* t4 = (const float4*)(descs_t  + ((size_t)b * SS + s) * DD);
    const float4* r4 = (const float4*)(descs_rot + ((size_t)b * SS + s) * DD);
    const float4* w4t = (const float4*)(scene_w);
    const float4* w4r = (const float4*)(scene_w + DD);

    float4 a = t4[tid], w = w4t[tid];
    float acc = a.x*w.x + a.y*w.y + a.z*w.z + a.w*w.w;
    float4 a2 = r4[tid], w2 = w4r[tid];
    acc += a2.x*w2.x + a2.y*w2.y + a2.z*w2.z + a2.w*w2.w;

    #pragma unroll
    for (int off = 32; off >= 1; off >>= 1) acc += __shfl_xor(acc, off, 64);

    __shared__ float red[4];
    if (lane == 0) red[wave] = acc;
    __syncthreads();
    if (tid == 0) logits[b * SS + s] = red[0] + red[1] + red[2] + red[3];
}

// ---------------- Kernel A2: softmax/argmax/list-build (1 wave) ----------------
__global__ __launch_bounds__(64) void finalize_scene_kernel(
    const float* __restrict__ scene_b, float* __restrict__ logits,
    int* __restrict__ idx_ws, int* __restrict__ list, int* __restrict__ count,
    float* __restrict__ out)
{
    const int b = threadIdx.x;
    const float bias = scene_b[0];
    float lg[SS];
    float m = -1e30f; int am = 0;
    #pragma unroll
    for (int s = 0; s < SS; ++s) {
        lg[s] = logits[b * SS + s] + bias;
        if (lg[s] > m) { m = lg[s]; am = s; }   // first-max tie-break
    }
    float sum = 0.f;
    #pragma unroll
    for (int s = 0; s < SS; ++s) sum += expf(lg[s] - m);
    const float lse = m + logf(sum);
    #pragma unroll
    for (int s = 0; s < SS; ++s) out[BB * 7 + b * SS + s] = lg[s] - lse;
    idx_ws[b] = am;

    for (int s = 0; s < SS; ++s) {
        unsigned long long mk = __ballot(am == s);
        if (am == s) {
            int rank = __popcll(mk & ((1ull << b) - 1ull));
            list[s * BB + rank] = b;
        }
        if (b == 0) count[s] = (int)__popcll(mk);
    }
}

// ---------------- Kernel B: layer-1 matvec, grouped by scene ----------------
// Each block: (dsp, s, head). 256 threads own 4 consecutive H-columns each.
// Inner loop: 8-row register buffer of W (8 x 16B loads in flight), x2 unroll.
template<int DSPL>
__global__ __launch_bounds__(256) void layer1_kernel(
    const float* __restrict__ descs_t, const float* __restrict__ descs_rot,
    const float* __restrict__ Wt1, const float* __restrict__ Wr1,
    const int* __restrict__ list, const int* __restrict__ count,
    float* __restrict__ part)
{
    constexpr int DS = DD / DSPL;      // rows per block
    const int dsp  = blockIdx.x;
    const int s    = blockIdx.y;
    const int head = blockIdx.z;
    const int tid  = threadIdx.x;

    const int cnt = count[s];
    if (cnt == 0) return;

    __shared__ int   sh_list[BB];
    __shared__ float sh_g[PMAX][DS];
    if (tid < BB) sh_list[tid] = list[s * BB + tid];

    const float* descs = head ? descs_rot : descs_t;
    const float* W = (head ? Wr1 : Wt1) + (size_t)s * DD * HH;
    const int j  = tid * 4;
    const int d0 = dsp * DS;

    for (int p0 = 0; p0 < cnt; p0 += PMAX) {
        const int nb = min(PMAX, cnt - p0);
        __syncthreads();
        // stage g slices (zero-pad absent samples -> branch-free compute)
        for (int t = tid; t < PMAX * (DS / 4); t += 256) {
            const int p = t / (DS / 4);
            const int c = t % (DS / 4);
            float4 v = make_float4(0.f, 0.f, 0.f, 0.f);
            if (p < nb) {
                const int b = sh_list[p0 + p];
                v = ((const float4*)(descs + ((size_t)b * SS + s) * DD + d0))[c];
            }
            ((float4*)sh_g[p])[c] = v;
        }
        __syncthreads();

        float4 acc[PMAX];
        #pragma unroll
        for (int p = 0; p < PMAX; ++p) acc[p] = make_float4(0.f, 0.f, 0.f, 0.f);

        const float* Wd = W + (size_t)d0 * HH + j;
        #pragma unroll 2
        for (int d8 = 0; d8 < DS / 8; ++d8) {
            float4 w[8];
            #pragma unroll
            for (int r = 0; r < 8; ++r)
                w[r] = *(const float4*)(Wd + (size_t)(d8 * 8 + r) * HH);
            #pragma unroll
            for (int h4 = 0; h4 < 2; ++h4) {
                #pragma unroll
                for (int p = 0; p < PMAX; ++p) {
                    float4 g = ((const float4*)sh_g[p])[d8 * 2 + h4];
                    acc[p].x += g.x * w[h4*4+0].x; acc[p].y += g.x * w[h4*4+0].y;
                    acc[p].z += g.x * w[h4*4+0].z; acc[p].w += g.x * w[h4*4+0].w;
                    acc[p].x += g.y * w[h4*4+1].x; acc[p].y += g.y * w[h4*4+1].y;
                    acc[p].z += g.y * w[h4*4+1].z; acc[p].w += g.y * w[h4*4+1].w;
                    acc[p].x += g.z * w[h4*4+2].x; acc[p].y += g.z * w[h4*4+2].y;
                    acc[p].z += g.z * w[h4*4+2].z; acc[p].w += g.z * w[h4*4+2].w;
                    acc[p].x += g.w * w[h4*4+3].x; acc[p].y += g.w * w[h4*4+3].y;
                    acc[p].z += g.w * w[h4*4+3].z; acc[p].w += g.w * w[h4*4+3].w;
                }
            }
        }

        #pragma unroll
        for (int p = 0; p < PMAX; ++p) {
            if (p < nb) {
                const int b = sh_list[p0 + p];
                float* dst = part + (((size_t)(head * BB + b) * DSPL + dsp) * HH) + j;
                *(float4*)dst = acc[p];
            }
        }
    }
}

// ---------------- Kernel C: bias + GELU + layer-2 + pose output ----------------
template<int DSPL>
__global__ __launch_bounds__(256) void head_out_kernel(
    const float* __restrict__ bt1, const float* __restrict__ Wt2, const float* __restrict__ bt2,
    const float* __restrict__ br1, const float* __restrict__ Wr2, const float* __restrict__ br2,
    const int* __restrict__ idx_ws, const float* __restrict__ part,
    float* __restrict__ out)
{
    const int b   = blockIdx.x;
    const int tid = threadIdx.x;
    const int s   = idx_ws[b];

    __shared__ float sh_h[2][HH];
    __shared__ float sh_red[7][4];

    #pragma unroll
    for (int head = 0; head < 2; ++head) {
        const float* b1 = (head ? br1 : bt1) + (size_t)s * HH;
        const float* p0 = part + ((size_t)(head * BB + b) * DSPL) * HH;
        const int j = tid * 4;
        float4 a = *(const float4*)(p0 + j);
        #pragma unroll
        for (int dsp = 1; dsp < DSPL; ++dsp) {
            float4 q = *(const float4*)(p0 + (size_t)dsp * HH + j);
            a.x += q.x; a.y += q.y; a.z += q.z; a.w += q.w;
        }
        float4 bb = *(const float4*)(b1 + j);
        sh_h[head][j + 0] = gelu_exact(a.x + bb.x);
        sh_h[head][j + 1] = gelu_exact(a.y + bb.y);
        sh_h[head][j + 2] = gelu_exact(a.z + bb.z);
        sh_h[head][j + 3] = gelu_exact(a.w + bb.w);
    }
    __syncthreads();

    const float* wt2 = Wt2 + (size_t)s * HH * 3;
    const float* wr2 = Wr2 + (size_t)s * HH * 4;
    float pa[7] = {0.f, 0.f, 0.f, 0.f, 0.f, 0.f, 0.f};
    for (int j = tid; j < HH; j += 256) {
        float ht = sh_h[0][j];
        float hr = sh_h[1][j];
        pa[0] += ht * wt2[j * 3 + 0];
        pa[1] += ht * wt2[j * 3 + 1];
        pa[2] += ht * wt2[j * 3 + 2];
        pa[3] += hr * wr2[j * 4 + 0];
        pa[4] += hr * wr2[j * 4 + 1];
        pa[5] += hr * wr2[j * 4 + 2];
        pa[6] += hr * wr2[j * 4 + 3];
    }
    const int lane = tid & 63, wave = tid >> 6;
    #pragma unroll
    for (int o = 0; o < 7; ++o) {
        float v = pa[o];
        #pragma unroll
        for (int off = 32; off >= 1; off >>= 1) v += __shfl_xor(v, off, 64);
        if (lane == 0) sh_red[o][wave] = v;
    }
    __syncthreads();
    if (tid < 7) {
        float v = sh_red[tid][0] + sh_red[tid][1] + sh_red[tid][2] + sh_red[tid][3];
        float bias = (tid < 3) ? bt2[(size_t)s * 3 + tid] : br2[(size_t)s * 4 + (tid - 3)];
        out[b * 7 + tid] = v + bias;
    }
}

template<int DSPL>
static void launch_pipeline(const float* descs_t, const float* descs_rot,
                            const float* Wt1, const float* Wr1,
                            const float* bt1, const float* Wt2, const float* bt2,
                            const float* br1, const float* Wr2, const float* br2,
                            int* idx_ws, int* list, int* count, float* part,
                            float* out, hipStream_t stream) {
    layer1_kernel<DSPL><<<dim3(DSPL, SS, 2), dim3(256), 0, stream>>>(
        descs_t, descs_rot, Wt1, Wr1, list, count, part);
    head_out_kernel<DSPL><<<dim3(BB), dim3(256), 0, stream>>>(
        bt1, Wt2, bt2, br1, Wr2, br2, idx_ws, part, out);
}

extern "C" void kernel_launch(void* const* d_in, const int* in_sizes, int n_in,
                              void* d_out, int out_size, void* d_ws, size_t ws_size,
                              hipStream_t stream) {
    const float* descs_t   = (const float*)d_in[0];
    const float* descs_rot = (const float*)d_in[1];
    const float* scene_w   = (const float*)d_in[2];
    const float* scene_b   = (const float*)d_in[3];
    const float* Wt1 = (const float*)d_in[4];
    const float* bt1 = (const float*)d_in[5];
    const float* Wt2 = (const float*)d_in[6];
    const float* bt2 = (const float*)d_in[7];
    const float* Wr1 = (const float*)d_in[8];
    const float* br1 = (const float*)d_in[9];
    const float* Wr2 = (const float*)d_in[10];
    const float* br2 = (const float*)d_in[11];
    float* out = (float*)d_out;

    int*   idx_ws = (int*)d_ws;
    float* logits = (float*)((char*)d_ws + WS_LOGITS);
    int*   list   = (int*)((char*)d_ws + WS_LIST);
    int*   count  = (int*)((char*)d_ws + WS_COUNT);
    float* part   = (float*)((char*)d_ws + WS_PART);

    logits_kernel<<<dim3(SS, BB), dim3(256), 0, stream>>>(
        descs_t, descs_rot, scene_w, logits);
    finalize_scene_kernel<<<dim3(1), dim3(64), 0, stream>>>(
        scene_b, logits, idx_ws, list, count, out);

    const size_t need16 = (size_t)WS_PART + (size_t)2 * BB * 16 * HH * sizeof(float);
    const size_t need8  = (size_t)WS_PART + (size_t)2 * BB * 8  * HH * sizeof(float);
    if (ws_size >= need16) {
        launch_pipeline<16>(descs_t, descs_rot, Wt1, Wr1, bt1, Wt2, bt2, br1, Wr2, br2,
                            idx_ws, list, count, part, out, stream);
    } else if (ws_size >= need8) {
        launch_pipeline<8>(descs_t, descs_rot, Wt1, Wr1, bt1, Wt2, bt2, br1, Wr2, br2,
                            idx_ws, list, count, part, out, stream);
    } else {
        launch_pipeline<4>(descs_t, descs_rot, Wt1, Wr1, bt1, Wt2, bt2, br1, Wr2, br2,
                            idx_ws, list, count, part, out, stream);
    }
}